// Round 6
// baseline (370.024 us; speedup 1.0000x reference)
//
#include <hip/hip_runtime.h>
#include <math.h>

#define N_NODES 2000
#define NA 16
#define NOBS 64
#define NH 128
#define NE 16000
#define NITERS 8

// ---------------- workspace layout (float offsets) ----------------
#define WS_MSG       0                       // f16-split p weights (mp keeps msgs in regs)
#define WS_FLAGS     300000                  // barrier flags: 500*32 + 8*32 ints (zeroed each run)
#define WS_Q         512000                  // q[8] (+pad, zeroed each run)
#define WS_SBUF      512016                  // 9 x 32000 uS buffers (u-initialized by umlp)
#define WS_AIDX      800016                  // int[8*2000]
#define WS_W         816016                  // int[16000] wflag
#define WS_PT        832016                  // pT 4,096,000; owner map (4,000,000 ints) aliases
#define WS_GIT       (WS_PT + 4000000)       // gru wihT k-panel 80x384 = 30720 (dead after gru)
#define WS_GHT       (WS_GIT + 30720)        // gru whhT k-panel 128x384 = 49152 (ends < WS_WB)
#define WS_WB        4928016                 // transposed fp32 weights (umlp only)
#define WS_UW0T      (WS_WB + 0)             // 128x256
#define WS_UWCAT     (WS_WB + 32768)         // 128x256  [W0a@h | W0b@h] combined
#define WS_UW1T      (WS_WB + 65536)         // 256x256
#define WS_UW2T      (WS_WB + 131072)        // 256x16   (ping-pong OOB reads land in dead area: benign)
#define WS_CAB       (WS_WB + 241664)        // cab[2000][256] = 512000

// f16 weight offsets (in _Float16 units) within WS_MSG region:
#define F16_W1H 0        // [256][128]
#define F16_W1L 32768
#define F16_W2H 65536    // [256][256]
#define F16_W2L 131072
#define F16_W3H 196608   // [16][256]
#define F16_W3L 200704
#define F16_W4H 204800   // [256][32] (k padded 16->32 with zeros)
#define F16_W4L 212992
// end 221184 f16 = 110592 floats  (< WS_FLAGS: fits inside msg region)

#define NBLK 500         // mp_fused grid; gen8 lines start at flags + NBLK*32

typedef _Float16 half8 __attribute__((ext_vector_type(8)));
typedef float f32x4 __attribute__((ext_vector_type(4)));

// ---------------- setup (blocks 0..1023) + init_owner (1024..1086) -----------
__global__ __launch_bounds__(256) void setup_kernel(
    float* __restrict__ ws, const int* __restrict__ edges,
    const float* __restrict__ uW0, const float* __restrict__ uW1,
    const float* __restrict__ uW2, const float* __restrict__ pW0,
    const float* __restrict__ pW1, const float* __restrict__ pW2,
    const float* __restrict__ pW3, const float* __restrict__ pW4,
    const float* __restrict__ gwih, const float* __restrict__ gwhh)
{
    if (blockIdx.x >= 1024) {
        int e = (blockIdx.x - 1024) * 256 + threadIdx.x;
        if (e < NE) {
            int i = edges[2 * e], j = edges[2 * e + 1];
            ((int*)(ws + WS_PT))[i * N_NODES + j] = -1;
        }
        return;
    }
    // tasks: 16 (q zero) + 135168 (fp32 weights) + 79888 (gru panels+pad)
    //        + 110592 (f16 p weights) + 16256 (barrier flags + gen8 zero)
    const int total = 341904;
    for (int idx = blockIdx.x * 256 + threadIdx.x; idx < total;
         idx += 1024 * 256) {
        if (idx < 16) {
            ws[WS_Q + idx] = 0.f;            // q[8] + pad
        } else {
            int t = idx - 16;
            if (t < 135168) {
                float v;
                if (t < 32768) {
                    int k = t / 256, o = t % 256;           // uW0T
                    v = uW0[o * 128 + k];
                } else if (t < 65536) {
                    int q = t - 32768, k = q / 256, o = q % 256;  // UWCAT: split pW0
                    v = (o < 128) ? pW0[o * 256 + k]
                                  : pW0[(o - 128) * 256 + 128 + k];
                } else if (t < 131072) {
                    int q = t - 65536, k = q / 256, o = q % 256;  // uW1T
                    v = uW1[o * 256 + k];
                } else {
                    int q = t - 131072, k = q / 16, o = q % 16;   // uW2T
                    v = uW2[o * 256 + k];
                }
                ws[WS_WB + t] = v;
            } else if (t < 215056) {
                int q = t - 135168;
                if (q < 30720) {       // gru wihT k-panel
                    int k4 = q / 1536, r = q % 1536, g = r >> 2, c = r & 3;
                    ws[WS_GIT + q] = gwih[g * 80 + 4 * k4 + c];
                } else if (q < 79872) {
                    int q2 = q - 30720;
                    int k4 = q2 / 1536, r = q2 % 1536, g = r >> 2, c = r & 3;
                    ws[WS_GHT + q2] = gwhh[g * 128 + 4 * k4 + c];
                }
            } else if (t < 325648) {
                // f16 hi/lo split of p-MLP weights (stored [n][k] row-major)
                int q = t - 215056;
                if (q >= 110592) continue;
                _Float16* fw = (_Float16*)ws;   // WS_MSG = 0
                float v; int hoff, loff;
                if (q < 32768) {                 // pW1: [256][128]
                    v = pW1[q]; hoff = F16_W1H + q; loff = F16_W1L + q;
                } else if (q < 98304) {          // pW2: [256][256]
                    int z = q - 32768; v = pW2[z];
                    hoff = F16_W2H + z; loff = F16_W2L + z;
                } else if (q < 102400) {         // pW3: [16][256]
                    int z = q - 98304; v = pW3[z];
                    hoff = F16_W3H + z; loff = F16_W3L + z;
                } else {                         // pW4: [256][16] -> [256][32] padded
                    int z = q - 102400; int n = z >> 5, kk = z & 31;
                    v = (kk < 16) ? pW4[n * 16 + kk] : 0.f;
                    hoff = F16_W4H + z; loff = F16_W4L + z;
                }
                _Float16 hv = (_Float16)v;
                fw[hoff] = hv;
                fw[loff] = (_Float16)(v - (float)hv);
            } else {
                int qf = t - 325648;             // barrier flags + gen8: zero each run
                ((int*)(ws + WS_FLAGS))[qf] = 0;
            }
        }
    }
}

// ---------------- GRU: 32 rows/block, direct-h (no gi/gh LDS) ---------------
// blocks 0..62 compute; 63..94 claim. Thread owns column c (= tid&127) and
// 8 rows (rh = tid>>7). 4 gate accumulators per row in VGPRs. Weight panels
// read once per block (63 blocks x 320KB = 20 MB, was 80 MB at 8 rows).
// Wave lanes share rh -> enc/hp reads broadcast; weight reads coalesced.
__global__ __launch_bounds__(512) void gru_kernel(
    const float* __restrict__ x, const float* __restrict__ pa,
    const float* __restrict__ st, const float* __restrict__ wihT,
    const float* __restrict__ whhT, const float* __restrict__ bih,
    const float* __restrict__ bhh, float* __restrict__ h_out,
    const int* __restrict__ edges, int* __restrict__ owner)
{
    if (blockIdx.x >= 63) {
        int e = (blockIdx.x - 63) * 512 + threadIdx.x;
        if (e < NE) {
            int i = edges[2 * e], j = edges[2 * e + 1];
            atomicMax(&owner[i * N_NODES + j], e);
        }
        return;
    }
    __shared__ float enc[32][80];
    __shared__ float hp[32][128];
    const int tid = threadIdx.x;
    const int n0 = blockIdx.x * 32;

    for (int idx = tid; idx < 32 * 80; idx += 512) {
        int r = idx / 80, c = idx % 80;
        int n = (n0 + r < N_NODES) ? n0 + r : N_NODES - 1;
        enc[r][c] = (c < 64) ? x[n * 64 + c] : pa[n * 16 + (c - 64)];
    }
    for (int idx = tid; idx < 32 * 128; idx += 512) {
        int r = idx >> 7, c = idx & 127;
        int n = (n0 + r < N_NODES) ? n0 + r : N_NODES - 1;
        hp[r][c] = st[n * 128 + c];
    }
    __syncthreads();

    const int c  = tid & 127;
    const int r0 = (tid >> 7) * 8;           // 0,8,16,24
    float accR[8], accZ[8], accNi[8], accNh[8];
    const float bR  = bih[c] + bhh[c];
    const float bZ  = bih[c + 128] + bhh[c + 128];
    const float bNi = bih[c + 256];
    const float bNh = bhh[c + 256];
    #pragma unroll
    for (int r = 0; r < 8; ++r) {
        accR[r] = bR; accZ[r] = bZ; accNi[r] = bNi; accNh[r] = bNh;
    }

    #pragma unroll 4
    for (int k4 = 0; k4 < 20; ++k4) {        // ih side
        const float4 wr = *(const float4*)&wihT[k4 * 1536 + c * 4];
        const float4 wz = *(const float4*)&wihT[k4 * 1536 + (c + 128) * 4];
        const float4 wn = *(const float4*)&wihT[k4 * 1536 + (c + 256) * 4];
        #pragma unroll
        for (int r = 0; r < 8; ++r) {
            const float4 ev = *(const float4*)&enc[r0 + r][4 * k4];
            accR[r]  = fmaf(ev.x, wr.x, fmaf(ev.y, wr.y, fmaf(ev.z, wr.z, fmaf(ev.w, wr.w, accR[r]))));
            accZ[r]  = fmaf(ev.x, wz.x, fmaf(ev.y, wz.y, fmaf(ev.z, wz.z, fmaf(ev.w, wz.w, accZ[r]))));
            accNi[r] = fmaf(ev.x, wn.x, fmaf(ev.y, wn.y, fmaf(ev.z, wn.z, fmaf(ev.w, wn.w, accNi[r]))));
        }
    }
    #pragma unroll 4
    for (int k4 = 0; k4 < 32; ++k4) {        // hh side
        const float4 wr = *(const float4*)&whhT[k4 * 1536 + c * 4];
        const float4 wz = *(const float4*)&whhT[k4 * 1536 + (c + 128) * 4];
        const float4 wn = *(const float4*)&whhT[k4 * 1536 + (c + 256) * 4];
        #pragma unroll
        for (int r = 0; r < 8; ++r) {
            const float4 hv = *(const float4*)&hp[r0 + r][4 * k4];
            accR[r]  = fmaf(hv.x, wr.x, fmaf(hv.y, wr.y, fmaf(hv.z, wr.z, fmaf(hv.w, wr.w, accR[r]))));
            accZ[r]  = fmaf(hv.x, wz.x, fmaf(hv.y, wz.y, fmaf(hv.z, wz.z, fmaf(hv.w, wz.w, accZ[r]))));
            accNh[r] = fmaf(hv.x, wn.x, fmaf(hv.y, wn.y, fmaf(hv.z, wn.z, fmaf(hv.w, wn.w, accNh[r]))));
        }
    }
    #pragma unroll
    for (int r = 0; r < 8; ++r) {
        int n = n0 + r0 + r;
        if (n < N_NODES) {
            float rr = 1.f / (1.f + expf(-accR[r]));
            float zz = 1.f / (1.f + expf(-accZ[r]));
            float nn = tanhf(accNi[r] + rr * accNh[r]);
            h_out[n * 128 + c] = (1.f - zz) * nn + zz * hp[r0 + r][c];
        }
    }
}

// ---------------- u MLP: 32 rows/block (u 0..62, cab 63..125, resolve 126..188)
// Weight traffic 200 MB -> ~50 MB (4x fewer blocks each streaming full panels).
__global__ __launch_bounds__(256) void umlp_kernel(
    const float* __restrict__ h, const float* __restrict__ w0t,
    const float* __restrict__ b0, const float* __restrict__ w1t,
    const float* __restrict__ b1, const float* __restrict__ w2t,
    const float* __restrict__ b2, const float* __restrict__ wcat,
    float* __restrict__ u_out, float* __restrict__ Sbuf,
    float* __restrict__ cab, const int* __restrict__ edges,
    const int* __restrict__ owner, int* __restrict__ wflag)
{
    if (blockIdx.x >= 126) {
        int e = (blockIdx.x - 126) * 256 + threadIdx.x;
        if (e < NE) {
            int i = edges[2 * e], j = edges[2 * e + 1];
            wflag[e] = (owner[i * N_NODES + j] == e) ? 1 : 0;
        }
        return;
    }
    __shared__ float A[32][128];
    __shared__ float B[32][256];
    const int tid = threadIdx.x;
    const bool is_cab = blockIdx.x >= 63;
    const int n0 = (is_cab ? blockIdx.x - 63 : blockIdx.x) * 32;

    for (int idx = tid; idx < 32 * 128; idx += 256) {
        int r = idx >> 7, c = idx & 127;
        int n = (n0 + r < N_NODES) ? n0 + r : N_NODES - 1;
        A[r][c] = h[n * 128 + c];
    }
    __syncthreads();

    if (is_cab) {
        const int o = tid;
        const float* wp = wcat + o;
        float wA[4], wB[4];
        #pragma unroll
        for (int c = 0; c < 4; ++c) wA[c] = wp[c * 256];
        float acc[32];
        #pragma unroll
        for (int r = 0; r < 32; ++r) acc[r] = 0.f;
        for (int k4 = 0; k4 < 32; k4 += 2) {
            #pragma unroll
            for (int c = 0; c < 4; ++c) wB[c] = wp[(4 * (k4 + 1) + c) * 256];
            #pragma unroll
            for (int r = 0; r < 32; ++r) {
                const float4 av = *(const float4*)&A[r][4 * k4];
                acc[r] = fmaf(av.x, wA[0], fmaf(av.y, wA[1], fmaf(av.z, wA[2], fmaf(av.w, wA[3], acc[r]))));
            }
            #pragma unroll
            for (int c = 0; c < 4; ++c) wA[c] = wp[(4 * (k4 + 2) + c) * 256]; // benign OOB at last pair
            #pragma unroll
            for (int r = 0; r < 32; ++r) {
                const float4 av = *(const float4*)&A[r][4 * k4 + 4];
                acc[r] = fmaf(av.x, wB[0], fmaf(av.y, wB[1], fmaf(av.z, wB[2], fmaf(av.w, wB[3], acc[r]))));
            }
        }
        #pragma unroll
        for (int r = 0; r < 32; ++r)
            if (n0 + r < N_NODES) cab[(n0 + r) * 256 + o] = acc[r];
        return;
    }

    // L0: 128->256 relu, A->B
    {
        const int o = tid;
        const float* wp = w0t + o;
        float wA[4], wB[4];
        #pragma unroll
        for (int c = 0; c < 4; ++c) wA[c] = wp[c * 256];
        float acc[32];
        #pragma unroll
        for (int r = 0; r < 32; ++r) acc[r] = b0[o];
        for (int k4 = 0; k4 < 32; k4 += 2) {
            #pragma unroll
            for (int c = 0; c < 4; ++c) wB[c] = wp[(4 * (k4 + 1) + c) * 256];
            #pragma unroll
            for (int r = 0; r < 32; ++r) {
                const float4 av = *(const float4*)&A[r][4 * k4];
                acc[r] = fmaf(av.x, wA[0], fmaf(av.y, wA[1], fmaf(av.z, wA[2], fmaf(av.w, wA[3], acc[r]))));
            }
            #pragma unroll
            for (int c = 0; c < 4; ++c) wA[c] = wp[(4 * (k4 + 2) + c) * 256]; // benign OOB at last pair
            #pragma unroll
            for (int r = 0; r < 32; ++r) {
                const float4 av = *(const float4*)&A[r][4 * k4 + 4];
                acc[r] = fmaf(av.x, wB[0], fmaf(av.y, wB[1], fmaf(av.z, wB[2], fmaf(av.w, wB[3], acc[r]))));
            }
        }
        #pragma unroll
        for (int r = 0; r < 32; ++r) B[r][o] = fmaxf(acc[r], 0.f);
    }
    __syncthreads();
    // L1: 256->256 relu, B->B (register staged)
    {
        const int o = tid;
        const float* wp = w1t + o;
        float wA[4], wB[4];
        #pragma unroll
        for (int c = 0; c < 4; ++c) wA[c] = wp[c * 256];
        float acc[32];
        #pragma unroll
        for (int r = 0; r < 32; ++r) acc[r] = b1[o];
        for (int k4 = 0; k4 < 64; k4 += 2) {
            #pragma unroll
            for (int c = 0; c < 4; ++c) wB[c] = wp[(4 * (k4 + 1) + c) * 256];
            #pragma unroll
            for (int r = 0; r < 32; ++r) {
                const float4 av = *(const float4*)&B[r][4 * k4];
                acc[r] = fmaf(av.x, wA[0], fmaf(av.y, wA[1], fmaf(av.z, wA[2], fmaf(av.w, wA[3], acc[r]))));
            }
            #pragma unroll
            for (int c = 0; c < 4; ++c) wA[c] = wp[(4 * (k4 + 2) + c) * 256]; // benign OOB at last pair
            #pragma unroll
            for (int r = 0; r < 32; ++r) {
                const float4 av = *(const float4*)&B[r][4 * k4 + 4];
                acc[r] = fmaf(av.x, wB[0], fmaf(av.y, wB[1], fmaf(av.z, wB[2], fmaf(av.w, wB[3], acc[r]))));
            }
        }
        __syncthreads();
        #pragma unroll
        for (int r = 0; r < 32; ++r) B[r][o] = fmaxf(acc[r], 0.f);
    }
    __syncthreads();
    // L2: 256->16, /N, no relu (512 tasks over 256 threads); fan out to uS
    for (int idx = tid; idx < 512; idx += 256) {
        int r = idx >> 4, o = idx & 15;
        float acc = b2[o];
        for (int k4 = 0; k4 < 64; ++k4) {
            const float4 av = *(const float4*)&B[r][4 * k4];
            acc = fmaf(av.x, w2t[(4 * k4 + 0) * 16 + o],
                  fmaf(av.y, w2t[(4 * k4 + 1) * 16 + o],
                  fmaf(av.z, w2t[(4 * k4 + 2) * 16 + o],
                  fmaf(av.w, w2t[(4 * k4 + 3) * 16 + o], acc))));
        }
        if (n0 + r < N_NODES) {
            float val = acc * (1.f / N_NODES);
            int oidx = (n0 + r) * 16 + o;
            u_out[oidx] = val;
            #pragma unroll
            for (int t = 0; t < NITERS + 1; ++t) Sbuf[t * 32000 + oidx] = val;
        }
    }
}

// ---------------- p MLP: f16-split MFMA, 8 waves / 512 threads ---------------
__global__ __launch_bounds__(512, 6) void pmlp_kernel(
    const float* __restrict__ cab, const int* __restrict__ edges,
    const float* __restrict__ b0, const _Float16* __restrict__ fw,
    const float* __restrict__ b1, const float* __restrict__ b2,
    const float* __restrict__ b3, const float* __restrict__ b4,
    float* __restrict__ p_out, float* __restrict__ pT)
{
    __shared__ __align__(16) _Float16 Ah[32][264];
    __shared__ __align__(16) _Float16 Al[32][264];
    __shared__ float C16[32][16];
    __shared__ float redC[2][32][16];
    __shared__ int fi[32], se[32];

    const int tid  = threadIdx.x;
    const int e0   = blockIdx.x * 16;
    const int wid  = tid >> 6;        // wave 0..7
    const int lane = tid & 63;
    const int lrow = lane & 15;       // A row / B col / C col
    const int lgrp = lane >> 4;       // 0..3
    const int koff = 8 * lgrp;        // k-bijection base (same for A and B)

    if (tid < 16) {
        int i = edges[2 * (e0 + tid)], j = edges[2 * (e0 + tid) + 1];
        fi[2 * tid] = i;     se[2 * tid] = j;       // row 2s  = dir (i,j)
        fi[2 * tid + 1] = j; se[2 * tid + 1] = i;   // row 2s+1 = dir (j,i)
    }
    __syncthreads();

    // L0 (collapsed): relu(ca[fi] + cb[se] + b0) -> f16 hi/lo into Ah/Al[.][0..127]
    {
        const int cl = tid & 127;
        const int rh = tid >> 7;      // 0..3 -> 8 rows each
        const float bb = b0[cl];
        #pragma unroll 4
        for (int r = rh * 8; r < rh * 8 + 8; ++r) {
            float v = cab[fi[r] * 256 + cl] + cab[se[r] * 256 + 128 + cl] + bb;
            v = fmaxf(v, 0.f);
            _Float16 hv = (_Float16)v;
            Ah[r][cl] = hv;
            Al[r][cl] = (_Float16)(v - (float)hv);
        }
    }
    __syncthreads();

    f32x4 acc[2][2];

    // ---- L1: [32x128] @ W1 -> [32x256] relu (MFMA, 48/wave) ----
    #pragma unroll
    for (int mt = 0; mt < 2; ++mt)
        #pragma unroll
        for (int nt = 0; nt < 2; ++nt) acc[mt][nt] = (f32x4){0.f, 0.f, 0.f, 0.f};
    #pragma unroll
    for (int ks = 0; ks < 4; ++ks) {
        half8 ah[2], al[2];
        #pragma unroll
        for (int mt = 0; mt < 2; ++mt) {
            ah[mt] = *(const half8*)&Ah[16 * mt + lrow][32 * ks + koff];
            al[mt] = *(const half8*)&Al[16 * mt + lrow][32 * ks + koff];
        }
        #pragma unroll
        for (int nt = 0; nt < 2; ++nt) {
            const int n = 32 * wid + 16 * nt + lrow;
            half8 bh = *(const half8*)(fw + F16_W1H + n * 128 + 32 * ks + koff);
            half8 bl = *(const half8*)(fw + F16_W1L + n * 128 + 32 * ks + koff);
            #pragma unroll
            for (int mt = 0; mt < 2; ++mt) {
                acc[mt][nt] = __builtin_amdgcn_mfma_f32_16x16x32_f16(ah[mt], bh, acc[mt][nt], 0, 0, 0);
                acc[mt][nt] = __builtin_amdgcn_mfma_f32_16x16x32_f16(ah[mt], bl, acc[mt][nt], 0, 0, 0);
                acc[mt][nt] = __builtin_amdgcn_mfma_f32_16x16x32_f16(al[mt], bh, acc[mt][nt], 0, 0, 0);
            }
        }
    }
    __syncthreads();
    #pragma unroll
    for (int nt = 0; nt < 2; ++nt) {
        const int col = 32 * wid + 16 * nt + lrow;
        const float bv = b1[col];
        #pragma unroll
        for (int mt = 0; mt < 2; ++mt) {
            #pragma unroll
            for (int r = 0; r < 4; ++r) {
                const int row = 16 * mt + 4 * lgrp + r;   // C: row=(lane>>4)*4+reg
                float v = fmaxf(acc[mt][nt][r] + bv, 0.f);
                _Float16 hv = (_Float16)v;
                Ah[row][col] = hv;
                Al[row][col] = (_Float16)(v - (float)hv);
            }
        }
    }
    __syncthreads();

    // ---- L2: [32x256] @ W2 -> [32x256] relu (MFMA, 96/wave) ----
    #pragma unroll
    for (int mt = 0; mt < 2; ++mt)
        #pragma unroll
        for (int nt = 0; nt < 2; ++nt) acc[mt][nt] = (f32x4){0.f, 0.f, 0.f, 0.f};
    for (int ks = 0; ks < 8; ++ks) {
        half8 ah[2], al[2];
        #pragma unroll
        for (int mt = 0; mt < 2; ++mt) {
            ah[mt] = *(const half8*)&Ah[16 * mt + lrow][32 * ks + koff];
            al[mt] = *(const half8*)&Al[16 * mt + lrow][32 * ks + koff];
        }
        #pragma unroll
        for (int nt = 0; nt < 2; ++nt) {
            const int n = 32 * wid + 16 * nt + lrow;
            half8 bh = *(const half8*)(fw + F16_W2H + n * 256 + 32 * ks + koff);
            half8 bl = *(const half8*)(fw + F16_W2L + n * 256 + 32 * ks + koff);
            #pragma unroll
            for (int mt = 0; mt < 2; ++mt) {
                acc[mt][nt] = __builtin_amdgcn_mfma_f32_16x16x32_f16(ah[mt], bh, acc[mt][nt], 0, 0, 0);
                acc[mt][nt] = __builtin_amdgcn_mfma_f32_16x16x32_f16(ah[mt], bl, acc[mt][nt], 0, 0, 0);
                acc[mt][nt] = __builtin_amdgcn_mfma_f32_16x16x32_f16(al[mt], bh, acc[mt][nt], 0, 0, 0);
            }
        }
    }
    __syncthreads();
    #pragma unroll
    for (int nt = 0; nt < 2; ++nt) {
        const int col = 32 * wid + 16 * nt + lrow;
        const float bv = b2[col];
        #pragma unroll
        for (int mt = 0; mt < 2; ++mt) {
            #pragma unroll
            for (int r = 0; r < 4; ++r) {
                const int row = 16 * mt + 4 * lgrp + r;
                float v = fmaxf(acc[mt][nt][r] + bv, 0.f);
                _Float16 hv = (_Float16)v;
                Ah[row][col] = hv;
                Al[row][col] = (_Float16)(v - (float)hv);
            }
        }
    }
    __syncthreads();

    // ---- L3: [32x256] @ W3 -> [32x16] relu (waves 0..3; 12 MFMA + reduce) ----
    if (wid < 4) {
        const int mt = wid & 1, kh = wid >> 1;
        f32x4 acc3 = {0.f, 0.f, 0.f, 0.f};
        #pragma unroll
        for (int ks = 4 * kh; ks < 4 * kh + 4; ++ks) {
            half8 ah = *(const half8*)&Ah[16 * mt + lrow][32 * ks + koff];
            half8 al = *(const half8*)&Al[16 * mt + lrow][32 * ks + koff];
            half8 bh = *(const half8*)(fw + F16_W3H + lrow * 256 + 32 * ks + koff);
            half8 bl = *(const half8*)(fw + F16_W3L + lrow * 256 + 32 * ks + koff);
            acc3 = __builtin_amdgcn_mfma_f32_16x16x32_f16(ah, bh, acc3, 0, 0, 0);
            acc3 = __builtin_amdgcn_mfma_f32_16x16x32_f16(ah, bl, acc3, 0, 0, 0);
            acc3 = __builtin_amdgcn_mfma_f32_16x16x32_f16(al, bh, acc3, 0, 0, 0);
        }
        #pragma unroll
        for (int r = 0; r < 4; ++r)
            redC[kh][16 * mt + 4 * lgrp + r][lrow] = acc3[r];
    }
    __syncthreads();
    {
        int r = tid >> 4, o = tid & 15;   // 512 threads = 512 tasks
        C16[r][o] = fmaxf(redC[0][r][o] + redC[1][r][o] + b3[o], 0.f);
    }
    __syncthreads();

    // ---- L4: [32x16] @ W4 -> [32x256], combine dirs, /E (MFMA, 12/wave) ----
    {
        half8 a4h[2], a4l[2];
        #pragma unroll
        for (int mt = 0; mt < 2; ++mt) {
            half8 hh, ll;
            #pragma unroll
            for (int j = 0; j < 8; ++j) { hh[j] = (_Float16)0.f; ll[j] = (_Float16)0.f; }
            if (lgrp < 2) {   // k = 8*lgrp + j in [0,16); k>=16 lanes carry zeros (padded)
                #pragma unroll
                for (int j = 0; j < 8; ++j) {
                    float v = C16[16 * mt + lrow][8 * lgrp + j];
                    _Float16 hv = (_Float16)v;
                    hh[j] = hv;
                    ll[j] = (_Float16)(v - (float)hv);
                }
            }
            a4h[mt] = hh; a4l[mt] = ll;
        }
        #pragma unroll
        for (int nt = 0; nt < 2; ++nt) {
            const int o = 32 * wid + 16 * nt + lrow;
            const float b4v = b4[o];
            half8 bh = *(const half8*)(fw + F16_W4H + o * 32 + koff);
            half8 bl = *(const half8*)(fw + F16_W4L + o * 32 + koff);
            const int ot = (o & 15) * 16 + (o >> 4);   // pT[e][aj][ai]
            #pragma unroll
            for (int mt = 0; mt < 2; ++mt) {
                f32x4 a4 = {0.f, 0.f, 0.f, 0.f};
                a4 = __builtin_amdgcn_mfma_f32_16x16x32_f16(a4h[mt], bh, a4, 0, 0, 0);
                a4 = __builtin_amdgcn_mfma_f32_16x16x32_f16(a4h[mt], bl, a4, 0, 0, 0);
                a4 = __builtin_amdgcn_mfma_f32_16x16x32_f16(a4l[mt], bh, a4, 0, 0, 0);
                const int s0 = 8 * mt + 2 * lgrp;      // rows (2s0,2s0+1),(2s0+2,2s0+3)
                float pa = (0.5f * (a4[0] + a4[1]) + b4v) * (1.f / NE);
                float pb = (0.5f * (a4[2] + a4[3]) + b4v) * (1.f / NE);
                p_out[(e0 + s0) * 256 + o] = pa;
                p_out[(e0 + s0 + 1) * 256 + o] = pb;
                pT[(e0 + s0) * 256 + ot] = pa;
                pT[(e0 + s0 + 1) * 256 + ot] = pb;
            }
        }
    }
}

// ---------------- contention-free software grid barrier ----------------------
__device__ __forceinline__ void grid_bar(int* flags, int gval)
{
    int* gen8 = flags + NBLK * 32;
    __syncthreads();
    if (blockIdx.x == 0) {
        const int i = threadIdx.x;
        if (i >= 1 && i < NBLK) {
            while (__hip_atomic_load(&flags[i * 32], __ATOMIC_RELAXED,
                                     __HIP_MEMORY_SCOPE_AGENT) < gval)
                __builtin_amdgcn_s_sleep(2);
        }
        __syncthreads();
        if (i < 8)
            __hip_atomic_store(&gen8[i * 32], gval, __ATOMIC_RELAXED,
                               __HIP_MEMORY_SCOPE_AGENT);
    } else {
        if (threadIdx.x == 0) {
            asm volatile("s_waitcnt vmcnt(0)" ::: "memory");
            __hip_atomic_store(&flags[blockIdx.x * 32], gval, __ATOMIC_RELAXED,
                               __HIP_MEMORY_SCOPE_AGENT);
            while (__hip_atomic_load(&gen8[(blockIdx.x & 7) * 32],
                                     __ATOMIC_RELAXED,
                                     __HIP_MEMORY_SCOPE_AGENT) < gval)
                __builtin_amdgcn_s_sleep(2);
        }
        __syncthreads();
    }
}

// ---------------- fused MP: 8 edge iters -> node-all -> final ----------------
__global__ __launch_bounds__(512, 4) void mp_fused_kernel(
    const float* __restrict__ u, float* __restrict__ Sbuf,
    const float* __restrict__ pT, const float* __restrict__ p,
    const int* __restrict__ edges, const int* __restrict__ wflag,
    int* __restrict__ aidx, float* __restrict__ q,
    float* __restrict__ a_out, float* __restrict__ q_out,
    int* __restrict__ flags)
{
    const int tid = threadIdx.x;
    const int bid = blockIdx.x;
    const int e   = bid * 32 + (tid >> 4);   // 0..15999
    const int L   = tid & 15;

    // ---- persistent per-edge state (registers) ----
    const int gi = edges[2 * e], gj = edges[2 * e + 1];
    const int wf = wflag[e];
    const float4* pt = (const float4*)(pT + e * 256 + L * 16);
    const float4 p0 = pt[0], p1 = pt[1], p2 = pt[2], p3 = pt[3];
    float pv[16] = {p0.x, p0.y, p0.z, p0.w, p1.x, p1.y, p1.z, p1.w,
                    p2.x, p2.y, p2.z, p2.w, p3.x, p3.y, p3.z, p3.w};
    float vmax = -INFINITY;
    #pragma unroll
    for (int a = 0; a < 16; ++a) vmax = fmaxf(vmax, pv[a]);
    float mold_ij = 0.f, mold_ji = 0.f;      // prior mi / mj (replaces msg[])

    for (int t = 0; t < NITERS; ++t) {
        // ---- edge phase, iter t ----
        const float* uSo = Sbuf + t * 32000;
        float* uSn = Sbuf + (t + 1) * 32000;
        const float bi = uSo[gi * 16 + L] - mold_ij;
        const float bj = uSo[gj * 16 + L] - mold_ji;
        float mj = -INFINITY;
        #pragma unroll
        for (int a = 0; a < 16; ++a)
            mj = fmaxf(mj, pv[a] + __shfl(bi, a, 16));
        float mi = vmax + bj;
        float sj = mj, si = mi;
        #pragma unroll
        for (int off = 1; off < 16; off <<= 1) {
            sj += __shfl_xor(sj, off, 16);
            si += __shfl_xor(si, off, 16);
        }
        mj -= sj * (1.f / 16.f);
        mi -= si * (1.f / 16.f);
        mold_ji = mj;
        mold_ij = mi;
        if (wf) {
            atomicAdd(&uSn[gj * 16 + L], mj);
            atomicAdd(&uSn[gi * 16 + L], mi);
        }
        grid_bar(flags, t + 1);              // Sbuf[t+1] complete
    }

    // ---- node-all: blocks 0..287, one t per 36-block group ----
    if (bid < 288) {
        const int t2 = bid / 36;             // 0..7
        const int r2 = (bid % 36) * 512 + tid;
        const float* Sn = Sbuf + (t2 + 1) * 32000;   // = u + S[t2]
        float partial = 0.f;
        if (r2 < N_NODES) {
            int n = r2;
            float bv = Sn[n * 16];
            int best = 0;
            #pragma unroll
            for (int a = 1; a < 16; ++a) {
                float v = Sn[n * 16 + a];
                if (v > bv) { bv = v; best = a; }
            }
            __hip_atomic_store(&aidx[t2 * N_NODES + n], best, __ATOMIC_RELAXED,
                               __HIP_MEMORY_SCOPE_AGENT);   // L2-bypass store
            partial = u[n * 16 + best];
        } else if (r2 < N_NODES + NE) {
            int ee = r2 - N_NODES;
            int ii = edges[2 * ee], jj = edges[2 * ee + 1];
            float bvi = Sn[ii * 16]; int ai = 0;
            #pragma unroll
            for (int a = 1; a < 16; ++a) {
                float v = Sn[ii * 16 + a];
                if (v > bvi) { bvi = v; ai = a; }
            }
            float bvj = Sn[jj * 16]; int aj = 0;
            #pragma unroll
            for (int a = 1; a < 16; ++a) {
                float v = Sn[jj * 16 + a];
                if (v > bvj) { bvj = v; aj = a; }
            }
            partial = p[ee * 256 + ai * 16 + aj];
        }
        #pragma unroll
        for (int off = 1; off < 64; off <<= 1)
            partial += __shfl_xor(partial, off, 64);
        if ((tid & 63) == 0) atomicAdd(&q[t2], partial);
    }
    grid_bar(flags, NITERS + 1);             // all q[t], aidx final

    // ---- final: running strict-> max over iters, one-hot a ----
    const int r = bid * 512 + tid;
    if (r < N_NODES * 16) {
        float cur = 0.f; int best_t = -1;
        #pragma unroll
        for (int t2 = 0; t2 < NITERS; ++t2) {
            float qv = q[t2];
            if (qv > cur) { cur = qv; best_t = t2; }
        }
        int n = r >> 4, c = r & 15;
        float val = 0.f;
        if (best_t >= 0 && aidx[best_t * N_NODES + n] == c) val = 1.f;
        a_out[r] = val;
        if (r == 0) q_out[0] = cur;
    }
}

extern "C" void kernel_launch(void* const* d_in, const int* in_sizes, int n_in,
                              void* d_out, int out_size, void* d_ws, size_t ws_size,
                              hipStream_t stream)
{
    (void)in_sizes; (void)n_in; (void)out_size; (void)ws_size;
    const float* x    = (const float*)d_in[0];
    const float* pa   = (const float*)d_in[1];
    const float* st   = (const float*)d_in[2];
    const int*   edges= (const int*)d_in[3];
    const float* gwih = (const float*)d_in[4];
    const float* gwhh = (const float*)d_in[5];
    const float* gbih = (const float*)d_in[6];
    const float* gbhh = (const float*)d_in[7];
    const float* uW0 = (const float*)d_in[8];  const float* ub0 = (const float*)d_in[9];
    const float* uW1 = (const float*)d_in[10]; const float* ub1 = (const float*)d_in[11];
    const float* uW2 = (const float*)d_in[12]; const float* ub2 = (const float*)d_in[13];
    const float* pW0 = (const float*)d_in[14]; const float* pb0 = (const float*)d_in[15];
    const float* pW1 = (const float*)d_in[16]; const float* pb1 = (const float*)d_in[17];
    const float* pW2 = (const float*)d_in[18]; const float* pb2 = (const float*)d_in[19];
    const float* pW3 = (const float*)d_in[20]; const float* pb3 = (const float*)d_in[21];
    const float* pW4 = (const float*)d_in[22]; const float* pb4 = (const float*)d_in[23];

    float* out   = (float*)d_out;
    float* a_out = out;                 // 32000
    float* q_out = out + 32000;         // 1
    float* u_out = out + 32001;         // 32000
    float* p_out = out + 64001;         // 4,096,000
    float* h_out = out + 4160001;       // 256,000 (state_out)

    float* ws   = (float*)d_ws;
    float* Sbuf = ws + WS_SBUF;
    float* q    = ws + WS_Q;
    int*   flg  = (int*)(ws + WS_FLAGS);
    int*   aidx = (int*)(ws + WS_AIDX);
    int*   wfl  = (int*)(ws + WS_W);
    float* pT   = ws + WS_PT;
    float* cab  = ws + WS_CAB;
    int*   owner= (int*)(ws + WS_PT);   // aliases pT; dead before pmlp runs

    setup_kernel<<<1087, 256, 0, stream>>>(ws, edges, uW0, uW1, uW2,
                                           pW0, pW1, pW2, pW3, pW4, gwih, gwhh);
    gru_kernel<<<95, 512, 0, stream>>>(x, pa, st, ws + WS_GIT, ws + WS_GHT,
                                       gbih, gbhh, h_out, edges, owner);
    umlp_kernel<<<189, 256, 0, stream>>>(h_out, ws + WS_UW0T, ub0,
                                         ws + WS_UW1T, ub1, ws + WS_UW2T, ub2,
                                         ws + WS_UWCAT, u_out, Sbuf, cab,
                                         edges, owner, wfl);
    pmlp_kernel<<<NE / 16, 512, 0, stream>>>(cab, edges, pb0,
                                             (const _Float16*)ws,
                                             pb1, pb2, pb3, pb4, p_out, pT);
    mp_fused_kernel<<<NBLK, 512, 0, stream>>>(u_out, Sbuf, pT, p_out,
                                              edges, wfl, aidx, q,
                                              a_out, q_out, flg);
}

// Round 7
// 280.116 us; speedup vs baseline: 1.3210x; 1.3210x over previous
//
#include <hip/hip_runtime.h>
#include <math.h>

#define N_NODES 2000
#define NA 16
#define NOBS 64
#define NH 128
#define NE 16000
#define NITERS 8

// ---------------- workspace layout (float offsets) ----------------
#define WS_MSG       0                       // f16-split p weights (mp keeps msgs in regs)
#define WS_FLAGS     300000                  // barrier flags: 500*32 + 8*32 ints (zeroed each run)
#define WS_Q         512000                  // q[8] (+pad, zeroed each run)
#define WS_SBUF      512016                  // 9 x 32000 uS buffers (u-initialized by umlp)
#define WS_AIDX      800016                  // int[8*2000]
#define WS_W         816016                  // int[16000] wflag
#define WS_PT        832016                  // pT 4,096,000; owner map (4,000,000 ints) aliases
#define WS_GIT       (WS_PT + 4000000)       // gru wihT k-panel 80x384 = 30720 (dead after gru)
#define WS_GHT       (WS_GIT + 30720)        // gru whhT k-panel 128x384 = 49152 (ends < WS_WB)
#define WS_WB        4928016                 // transposed fp32 weights (umlp only)
#define WS_UW0T      (WS_WB + 0)             // 128x256
#define WS_UWCAT     (WS_WB + 32768)         // 128x256  [W0a@h | W0b@h] combined
#define WS_UW1T      (WS_WB + 65536)         // 256x256
#define WS_UW2T      (WS_WB + 131072)        // 256x16   (ping-pong OOB reads land in dead area: benign)
#define WS_CAB       (WS_WB + 241664)        // cab[2000][256] = 512000

// f16 weight offsets (in _Float16 units) within WS_MSG region:
#define F16_W1H 0        // [256][128]
#define F16_W1L 32768
#define F16_W2H 65536    // [256][256]
#define F16_W2L 131072
#define F16_W3H 196608   // [16][256]
#define F16_W3L 200704
#define F16_W4H 204800   // [256][32] (k padded 16->32 with zeros)
#define F16_W4L 212992
// end 221184 f16 = 110592 floats  (< WS_FLAGS: fits inside msg region)

#define NBLK 500         // mp_fused grid; gen8 lines start at flags + NBLK*32

typedef _Float16 half8 __attribute__((ext_vector_type(8)));
typedef float f32x4 __attribute__((ext_vector_type(4)));

// ---------------- setup (blocks 0..1023) + init_owner (1024..1086) -----------
__global__ __launch_bounds__(256) void setup_kernel(
    float* __restrict__ ws, const int* __restrict__ edges,
    const float* __restrict__ uW0, const float* __restrict__ uW1,
    const float* __restrict__ uW2, const float* __restrict__ pW0,
    const float* __restrict__ pW1, const float* __restrict__ pW2,
    const float* __restrict__ pW3, const float* __restrict__ pW4,
    const float* __restrict__ gwih, const float* __restrict__ gwhh)
{
    if (blockIdx.x >= 1024) {
        int e = (blockIdx.x - 1024) * 256 + threadIdx.x;
        if (e < NE) {
            int i = edges[2 * e], j = edges[2 * e + 1];
            ((int*)(ws + WS_PT))[i * N_NODES + j] = -1;
        }
        return;
    }
    const int total = 341904;
    for (int idx = blockIdx.x * 256 + threadIdx.x; idx < total;
         idx += 1024 * 256) {
        if (idx < 16) {
            ws[WS_Q + idx] = 0.f;            // q[8] + pad
        } else {
            int t = idx - 16;
            if (t < 135168) {
                float v;
                if (t < 32768) {
                    int k = t / 256, o = t % 256;           // uW0T
                    v = uW0[o * 128 + k];
                } else if (t < 65536) {
                    int q = t - 32768, k = q / 256, o = q % 256;  // UWCAT: split pW0
                    v = (o < 128) ? pW0[o * 256 + k]
                                  : pW0[(o - 128) * 256 + 128 + k];
                } else if (t < 131072) {
                    int q = t - 65536, k = q / 256, o = q % 256;  // uW1T
                    v = uW1[o * 256 + k];
                } else {
                    int q = t - 131072, k = q / 16, o = q % 16;   // uW2T
                    v = uW2[o * 256 + k];
                }
                ws[WS_WB + t] = v;
            } else if (t < 215056) {
                int q = t - 135168;
                if (q < 30720) {       // gru wihT k-panel
                    int k4 = q / 1536, r = q % 1536, g = r >> 2, c = r & 3;
                    ws[WS_GIT + q] = gwih[g * 80 + 4 * k4 + c];
                } else if (q < 79872) {
                    int q2 = q - 30720;
                    int k4 = q2 / 1536, r = q2 % 1536, g = r >> 2, c = r & 3;
                    ws[WS_GHT + q2] = gwhh[g * 128 + 4 * k4 + c];
                }
            } else if (t < 325648) {
                // f16 hi/lo split of p-MLP weights (stored [n][k] row-major)
                int q = t - 215056;
                if (q >= 110592) continue;
                _Float16* fw = (_Float16*)ws;   // WS_MSG = 0
                float v; int hoff, loff;
                if (q < 32768) {                 // pW1: [256][128]
                    v = pW1[q]; hoff = F16_W1H + q; loff = F16_W1L + q;
                } else if (q < 98304) {          // pW2: [256][256]
                    int z = q - 32768; v = pW2[z];
                    hoff = F16_W2H + z; loff = F16_W2L + z;
                } else if (q < 102400) {         // pW3: [16][256]
                    int z = q - 98304; v = pW3[z];
                    hoff = F16_W3H + z; loff = F16_W3L + z;
                } else {                         // pW4: [256][16] -> [256][32] padded
                    int z = q - 102400; int n = z >> 5, kk = z & 31;
                    v = (kk < 16) ? pW4[n * 16 + kk] : 0.f;
                    hoff = F16_W4H + z; loff = F16_W4L + z;
                }
                _Float16 hv = (_Float16)v;
                fw[hoff] = hv;
                fw[loff] = (_Float16)(v - (float)hv);
            } else {
                int qf = t - 325648;             // barrier flags + gen8: zero each run
                ((int*)(ws + WS_FLAGS))[qf] = 0;
            }
        }
    }
}

// ---------------- GRU (blocks 0..249) + claim (250..312) ---------------------
// (round-5 version: 8 rows/block, 313 blocks -> high wave count; weights L2-hit)
__global__ __launch_bounds__(256) void gru_kernel(
    const float* __restrict__ x, const float* __restrict__ pa,
    const float* __restrict__ st, const float* __restrict__ wihT,
    const float* __restrict__ whhT, const float* __restrict__ bih,
    const float* __restrict__ bhh, float* __restrict__ h_out,
    const int* __restrict__ edges, int* __restrict__ owner)
{
    if (blockIdx.x >= 250) {
        int e = (blockIdx.x - 250) * 256 + threadIdx.x;
        if (e < NE) {
            int i = edges[2 * e], j = edges[2 * e + 1];
            atomicMax(&owner[i * N_NODES + j], e);
        }
        return;
    }
    __shared__ float enc[8][80];
    __shared__ float hp[8][128];
    __shared__ float gi[8][384];
    __shared__ float gh[8][384];
    const int tid = threadIdx.x;
    const int n0 = blockIdx.x * 8;

    for (int idx = tid; idx < 8 * 80; idx += 256) {
        int r = idx / 80, c = idx % 80;
        enc[r][c] = (c < 64) ? x[(n0 + r) * 64 + c] : pa[(n0 + r) * 16 + (c - 64)];
    }
    for (int idx = tid; idx < 8 * 128; idx += 256) {
        int r = idx >> 7, c = idx & 127;
        hp[r][c] = st[(n0 + r) * 128 + c];
    }
    __syncthreads();

    for (int idx = tid; idx < 8 * 384; idx += 256) {
        int g = idx % 384, r = idx / 384;
        float s1 = bih[g];
        #pragma unroll 5
        for (int k4 = 0; k4 < 20; ++k4) {
            const float4 ev = *(const float4*)&enc[r][4 * k4];
            const float4 wv = *(const float4*)&wihT[k4 * 1536 + g * 4];
            s1 = fmaf(ev.x, wv.x, fmaf(ev.y, wv.y, fmaf(ev.z, wv.z, fmaf(ev.w, wv.w, s1))));
        }
        gi[r][g] = s1;
        float s2 = bhh[g];
        #pragma unroll 8
        for (int k4 = 0; k4 < 32; ++k4) {
            const float4 hv = *(const float4*)&hp[r][4 * k4];
            const float4 wv = *(const float4*)&whhT[k4 * 1536 + g * 4];
            s2 = fmaf(hv.x, wv.x, fmaf(hv.y, wv.y, fmaf(hv.z, wv.z, fmaf(hv.w, wv.w, s2))));
        }
        gh[r][g] = s2;
    }
    __syncthreads();

    for (int idx = tid; idx < 8 * 128; idx += 256) {
        int r = idx >> 7, c = idx & 127;
        float rr = 1.f / (1.f + expf(-(gi[r][c] + gh[r][c])));
        float zz = 1.f / (1.f + expf(-(gi[r][128 + c] + gh[r][128 + c])));
        float nn = tanhf(gi[r][256 + c] + rr * gh[r][256 + c]);
        h_out[(n0 + r) * 128 + c] = (1.f - zz) * nn + zz * hp[r][c];
    }
}

// ---------------- u MLP (0..249) + cab (250..499) + resolve (500..562) -------
// (round-5 version: 8 rows/block -> high wave count; weights L2-hit)
__global__ __launch_bounds__(256) void umlp_kernel(
    const float* __restrict__ h, const float* __restrict__ w0t,
    const float* __restrict__ b0, const float* __restrict__ w1t,
    const float* __restrict__ b1, const float* __restrict__ w2t,
    const float* __restrict__ b2, const float* __restrict__ wcat,
    float* __restrict__ u_out, float* __restrict__ Sbuf,
    float* __restrict__ cab, const int* __restrict__ edges,
    const int* __restrict__ owner, int* __restrict__ wflag)
{
    if (blockIdx.x >= 500) {
        int e = (blockIdx.x - 500) * 256 + threadIdx.x;
        if (e < NE) {
            int i = edges[2 * e], j = edges[2 * e + 1];
            wflag[e] = (owner[i * N_NODES + j] == e) ? 1 : 0;
        }
        return;
    }
    __shared__ float A[8][128];
    __shared__ float B[8][256];
    const int tid = threadIdx.x;
    const bool is_cab = blockIdx.x >= 250;
    const int n0 = (is_cab ? blockIdx.x - 250 : blockIdx.x) * 8;

    for (int idx = tid; idx < 8 * 128; idx += 256) {
        int r = idx >> 7, c = idx & 127;
        A[r][c] = h[(n0 + r) * 128 + c];
    }
    __syncthreads();

    if (is_cab) {
        const int o = tid;
        const float* wp = wcat + o;
        float wA[4], wB[4];
        #pragma unroll
        for (int c = 0; c < 4; ++c) wA[c] = wp[c * 256];
        float acc[8];
        #pragma unroll
        for (int r = 0; r < 8; ++r) acc[r] = 0.f;
        for (int k4 = 0; k4 < 32; k4 += 2) {
            #pragma unroll
            for (int c = 0; c < 4; ++c) wB[c] = wp[(4 * (k4 + 1) + c) * 256];
            #pragma unroll
            for (int r = 0; r < 8; ++r) {
                const float4 av = *(const float4*)&A[r][4 * k4];
                acc[r] = fmaf(av.x, wA[0], fmaf(av.y, wA[1], fmaf(av.z, wA[2], fmaf(av.w, wA[3], acc[r]))));
            }
            #pragma unroll
            for (int c = 0; c < 4; ++c) wA[c] = wp[(4 * (k4 + 2) + c) * 256]; // benign OOB at last pair
            #pragma unroll
            for (int r = 0; r < 8; ++r) {
                const float4 av = *(const float4*)&A[r][4 * k4 + 4];
                acc[r] = fmaf(av.x, wB[0], fmaf(av.y, wB[1], fmaf(av.z, wB[2], fmaf(av.w, wB[3], acc[r]))));
            }
        }
        #pragma unroll
        for (int r = 0; r < 8; ++r) cab[(n0 + r) * 256 + o] = acc[r];
        return;
    }

    // L0: 128->256 relu, A->B
    {
        const int o = tid;
        const float* wp = w0t + o;
        float wA[4], wB[4];
        #pragma unroll
        for (int c = 0; c < 4; ++c) wA[c] = wp[c * 256];
        float acc[8];
        #pragma unroll
        for (int r = 0; r < 8; ++r) acc[r] = b0[o];
        for (int k4 = 0; k4 < 32; k4 += 2) {
            #pragma unroll
            for (int c = 0; c < 4; ++c) wB[c] = wp[(4 * (k4 + 1) + c) * 256];
            #pragma unroll
            for (int r = 0; r < 8; ++r) {
                const float4 av = *(const float4*)&A[r][4 * k4];
                acc[r] = fmaf(av.x, wA[0], fmaf(av.y, wA[1], fmaf(av.z, wA[2], fmaf(av.w, wA[3], acc[r]))));
            }
            #pragma unroll
            for (int c = 0; c < 4; ++c) wA[c] = wp[(4 * (k4 + 2) + c) * 256]; // benign OOB at last pair
            #pragma unroll
            for (int r = 0; r < 8; ++r) {
                const float4 av = *(const float4*)&A[r][4 * k4 + 4];
                acc[r] = fmaf(av.x, wB[0], fmaf(av.y, wB[1], fmaf(av.z, wB[2], fmaf(av.w, wB[3], acc[r]))));
            }
        }
        #pragma unroll
        for (int r = 0; r < 8; ++r) B[r][o] = fmaxf(acc[r], 0.f);
    }
    __syncthreads();
    // L1: 256->256 relu, B->B (register staged)
    {
        const int o = tid;
        const float* wp = w1t + o;
        float wA[4], wB[4];
        #pragma unroll
        for (int c = 0; c < 4; ++c) wA[c] = wp[c * 256];
        float acc[8];
        #pragma unroll
        for (int r = 0; r < 8; ++r) acc[r] = b1[o];
        for (int k4 = 0; k4 < 64; k4 += 2) {
            #pragma unroll
            for (int c = 0; c < 4; ++c) wB[c] = wp[(4 * (k4 + 1) + c) * 256];
            #pragma unroll
            for (int r = 0; r < 8; ++r) {
                const float4 av = *(const float4*)&B[r][4 * k4];
                acc[r] = fmaf(av.x, wA[0], fmaf(av.y, wA[1], fmaf(av.z, wA[2], fmaf(av.w, wA[3], acc[r]))));
            }
            #pragma unroll
            for (int c = 0; c < 4; ++c) wA[c] = wp[(4 * (k4 + 2) + c) * 256]; // benign OOB at last pair
            #pragma unroll
            for (int r = 0; r < 8; ++r) {
                const float4 av = *(const float4*)&B[r][4 * k4 + 4];
                acc[r] = fmaf(av.x, wB[0], fmaf(av.y, wB[1], fmaf(av.z, wB[2], fmaf(av.w, wB[3], acc[r]))));
            }
        }
        __syncthreads();
        #pragma unroll
        for (int r = 0; r < 8; ++r) B[r][o] = fmaxf(acc[r], 0.f);
    }
    __syncthreads();
    // L2: 256->16, /N, no relu (threads 0..127); fan out to u and 9 uS slots
    if (tid < 128) {
        int r = tid >> 4, o = tid & 15;
        float acc = b2[o];
        for (int k4 = 0; k4 < 64; ++k4) {
            const float4 av = *(const float4*)&B[r][4 * k4];
            acc = fmaf(av.x, w2t[(4 * k4 + 0) * 16 + o],
                  fmaf(av.y, w2t[(4 * k4 + 1) * 16 + o],
                  fmaf(av.z, w2t[(4 * k4 + 2) * 16 + o],
                  fmaf(av.w, w2t[(4 * k4 + 3) * 16 + o], acc))));
        }
        float val = acc * (1.f / N_NODES);
        int idx = (n0 + r) * 16 + o;
        u_out[idx] = val;
        #pragma unroll
        for (int t = 0; t < NITERS + 1; ++t) Sbuf[t * 32000 + idx] = val;
    }
}

// ---------------- p MLP: f16-split MFMA, 32 edges (64 rows) / block ----------
// 500 blocks x 512 threads, LDS 72.2 KB -> 2 blocks/CU (16 waves/CU, same
// occupancy as 16-edge version) but HALF the L2 weight streaming (~750->375MB)
// and 2x MFMA per weight fetch. L3: waves 0..3 own a 16-row tile with full K
// (no redC reduction buffer).
__global__ __launch_bounds__(512, 4) void pmlp_kernel(
    const float* __restrict__ cab, const int* __restrict__ edges,
    const float* __restrict__ b0, const _Float16* __restrict__ fw,
    const float* __restrict__ b1, const float* __restrict__ b2,
    const float* __restrict__ b3, const float* __restrict__ b4,
    float* __restrict__ p_out, float* __restrict__ pT)
{
    __shared__ __align__(16) _Float16 Ah[64][264];
    __shared__ __align__(16) _Float16 Al[64][264];
    __shared__ float C16[64][16];
    __shared__ int fi[64], se[64];

    const int tid  = threadIdx.x;
    const int e0   = blockIdx.x * 32;
    const int wid  = tid >> 6;        // wave 0..7
    const int lane = tid & 63;
    const int lrow = lane & 15;       // A row / B col / C col
    const int lgrp = lane >> 4;       // 0..3
    const int koff = 8 * lgrp;        // k-bijection base (same for A and B)

    if (tid < 32) {
        int i = edges[2 * (e0 + tid)], j = edges[2 * (e0 + tid) + 1];
        fi[2 * tid] = i;     se[2 * tid] = j;       // row 2s  = dir (i,j)
        fi[2 * tid + 1] = j; se[2 * tid + 1] = i;   // row 2s+1 = dir (j,i)
    }
    __syncthreads();

    // L0 (collapsed): relu(ca[fi] + cb[se] + b0) -> f16 hi/lo into Ah/Al[.][0..127]
    {
        const int cl = tid & 127;
        const int rh = tid >> 7;      // 0..3 -> 16 rows each
        const float bb = b0[cl];
        #pragma unroll 4
        for (int r = rh * 16; r < rh * 16 + 16; ++r) {
            float v = cab[fi[r] * 256 + cl] + cab[se[r] * 256 + 128 + cl] + bb;
            v = fmaxf(v, 0.f);
            _Float16 hv = (_Float16)v;
            Ah[r][cl] = hv;
            Al[r][cl] = (_Float16)(v - (float)hv);
        }
    }
    __syncthreads();

    f32x4 acc[4][2];

    // ---- L1: [64x128] @ W1 -> [64x256] relu (MFMA, 96/wave) ----
    #pragma unroll
    for (int mt = 0; mt < 4; ++mt)
        #pragma unroll
        for (int nt = 0; nt < 2; ++nt) acc[mt][nt] = (f32x4){0.f, 0.f, 0.f, 0.f};
    #pragma unroll
    for (int ks = 0; ks < 4; ++ks) {
        half8 ah[4], al[4];
        #pragma unroll
        for (int mt = 0; mt < 4; ++mt) {
            ah[mt] = *(const half8*)&Ah[16 * mt + lrow][32 * ks + koff];
            al[mt] = *(const half8*)&Al[16 * mt + lrow][32 * ks + koff];
        }
        #pragma unroll
        for (int nt = 0; nt < 2; ++nt) {
            const int n = 32 * wid + 16 * nt + lrow;
            half8 bh = *(const half8*)(fw + F16_W1H + n * 128 + 32 * ks + koff);
            half8 bl = *(const half8*)(fw + F16_W1L + n * 128 + 32 * ks + koff);
            #pragma unroll
            for (int mt = 0; mt < 4; ++mt) {
                acc[mt][nt] = __builtin_amdgcn_mfma_f32_16x16x32_f16(ah[mt], bh, acc[mt][nt], 0, 0, 0);
                acc[mt][nt] = __builtin_amdgcn_mfma_f32_16x16x32_f16(ah[mt], bl, acc[mt][nt], 0, 0, 0);
                acc[mt][nt] = __builtin_amdgcn_mfma_f32_16x16x32_f16(al[mt], bh, acc[mt][nt], 0, 0, 0);
            }
        }
    }
    __syncthreads();
    #pragma unroll
    for (int nt = 0; nt < 2; ++nt) {
        const int col = 32 * wid + 16 * nt + lrow;
        const float bv = b1[col];
        #pragma unroll
        for (int mt = 0; mt < 4; ++mt) {
            #pragma unroll
            for (int r = 0; r < 4; ++r) {
                const int row = 16 * mt + 4 * lgrp + r;   // C: row=(lane>>4)*4+reg
                float v = fmaxf(acc[mt][nt][r] + bv, 0.f);
                _Float16 hv = (_Float16)v;
                Ah[row][col] = hv;
                Al[row][col] = (_Float16)(v - (float)hv);
            }
        }
    }
    __syncthreads();

    // ---- L2: [64x256] @ W2 -> [64x256] relu (MFMA, 192/wave) ----
    #pragma unroll
    for (int mt = 0; mt < 4; ++mt)
        #pragma unroll
        for (int nt = 0; nt < 2; ++nt) acc[mt][nt] = (f32x4){0.f, 0.f, 0.f, 0.f};
    for (int ks = 0; ks < 8; ++ks) {
        half8 ah[4], al[4];
        #pragma unroll
        for (int mt = 0; mt < 4; ++mt) {
            ah[mt] = *(const half8*)&Ah[16 * mt + lrow][32 * ks + koff];
            al[mt] = *(const half8*)&Al[16 * mt + lrow][32 * ks + koff];
        }
        #pragma unroll
        for (int nt = 0; nt < 2; ++nt) {
            const int n = 32 * wid + 16 * nt + lrow;
            half8 bh = *(const half8*)(fw + F16_W2H + n * 256 + 32 * ks + koff);
            half8 bl = *(const half8*)(fw + F16_W2L + n * 256 + 32 * ks + koff);
            #pragma unroll
            for (int mt = 0; mt < 4; ++mt) {
                acc[mt][nt] = __builtin_amdgcn_mfma_f32_16x16x32_f16(ah[mt], bh, acc[mt][nt], 0, 0, 0);
                acc[mt][nt] = __builtin_amdgcn_mfma_f32_16x16x32_f16(ah[mt], bl, acc[mt][nt], 0, 0, 0);
                acc[mt][nt] = __builtin_amdgcn_mfma_f32_16x16x32_f16(al[mt], bh, acc[mt][nt], 0, 0, 0);
            }
        }
    }
    __syncthreads();
    #pragma unroll
    for (int nt = 0; nt < 2; ++nt) {
        const int col = 32 * wid + 16 * nt + lrow;
        const float bv = b2[col];
        #pragma unroll
        for (int mt = 0; mt < 4; ++mt) {
            #pragma unroll
            for (int r = 0; r < 4; ++r) {
                const int row = 16 * mt + 4 * lgrp + r;
                float v = fmaxf(acc[mt][nt][r] + bv, 0.f);
                _Float16 hv = (_Float16)v;
                Ah[row][col] = hv;
                Al[row][col] = (_Float16)(v - (float)hv);
            }
        }
    }
    __syncthreads();

    // ---- L3: [64x256] @ W3 -> [64x16] relu (waves 0..3, full K, 24 MFMA) ----
    if (wid < 4) {
        f32x4 acc3 = {0.f, 0.f, 0.f, 0.f};
        #pragma unroll
        for (int ks = 0; ks < 8; ++ks) {
            half8 ah = *(const half8*)&Ah[16 * wid + lrow][32 * ks + koff];
            half8 al = *(const half8*)&Al[16 * wid + lrow][32 * ks + koff];
            half8 bh = *(const half8*)(fw + F16_W3H + lrow * 256 + 32 * ks + koff);
            half8 bl = *(const half8*)(fw + F16_W3L + lrow * 256 + 32 * ks + koff);
            acc3 = __builtin_amdgcn_mfma_f32_16x16x32_f16(ah, bh, acc3, 0, 0, 0);
            acc3 = __builtin_amdgcn_mfma_f32_16x16x32_f16(ah, bl, acc3, 0, 0, 0);
            acc3 = __builtin_amdgcn_mfma_f32_16x16x32_f16(al, bh, acc3, 0, 0, 0);
        }
        const float b3v = b3[lrow];
        #pragma unroll
        for (int r = 0; r < 4; ++r)
            C16[16 * wid + 4 * lgrp + r][lrow] = fmaxf(acc3[r] + b3v, 0.f);
    }
    __syncthreads();

    // ---- L4: [64x16] @ W4 -> [64x256], combine dirs, /E (MFMA, 24/wave) ----
    {
        half8 a4h[4], a4l[4];
        #pragma unroll
        for (int mt = 0; mt < 4; ++mt) {
            half8 hh, ll;
            #pragma unroll
            for (int j = 0; j < 8; ++j) { hh[j] = (_Float16)0.f; ll[j] = (_Float16)0.f; }
            if (lgrp < 2) {   // k = 8*lgrp + j in [0,16); k>=16 lanes carry zeros (padded)
                #pragma unroll
                for (int j = 0; j < 8; ++j) {
                    float v = C16[16 * mt + lrow][8 * lgrp + j];
                    _Float16 hv = (_Float16)v;
                    hh[j] = hv;
                    ll[j] = (_Float16)(v - (float)hv);
                }
            }
            a4h[mt] = hh; a4l[mt] = ll;
        }
        #pragma unroll
        for (int nt = 0; nt < 2; ++nt) {
            const int o = 32 * wid + 16 * nt + lrow;
            const float b4v = b4[o];
            half8 bh = *(const half8*)(fw + F16_W4H + o * 32 + koff);
            half8 bl = *(const half8*)(fw + F16_W4L + o * 32 + koff);
            const int ot = (o & 15) * 16 + (o >> 4);   // pT[e][aj][ai]
            #pragma unroll
            for (int mt = 0; mt < 4; ++mt) {
                f32x4 a4 = {0.f, 0.f, 0.f, 0.f};
                a4 = __builtin_amdgcn_mfma_f32_16x16x32_f16(a4h[mt], bh, a4, 0, 0, 0);
                a4 = __builtin_amdgcn_mfma_f32_16x16x32_f16(a4h[mt], bl, a4, 0, 0, 0);
                a4 = __builtin_amdgcn_mfma_f32_16x16x32_f16(a4l[mt], bh, a4, 0, 0, 0);
                const int s0 = 8 * mt + 2 * lgrp;      // rows (2s0,2s0+1),(2s0+2,2s0+3)
                float pa = (0.5f * (a4[0] + a4[1]) + b4v) * (1.f / NE);
                float pb = (0.5f * (a4[2] + a4[3]) + b4v) * (1.f / NE);
                p_out[(e0 + s0) * 256 + o] = pa;
                p_out[(e0 + s0 + 1) * 256 + o] = pb;
                pT[(e0 + s0) * 256 + ot] = pa;
                pT[(e0 + s0 + 1) * 256 + ot] = pb;
            }
        }
    }
}

// ---------------- contention-free software grid barrier ----------------------
__device__ __forceinline__ void grid_bar(int* flags, int gval)
{
    int* gen8 = flags + NBLK * 32;
    __syncthreads();
    if (blockIdx.x == 0) {
        const int i = threadIdx.x;
        if (i >= 1 && i < NBLK) {
            while (__hip_atomic_load(&flags[i * 32], __ATOMIC_RELAXED,
                                     __HIP_MEMORY_SCOPE_AGENT) < gval)
                __builtin_amdgcn_s_sleep(2);
        }
        __syncthreads();
        if (i < 8)
            __hip_atomic_store(&gen8[i * 32], gval, __ATOMIC_RELAXED,
                               __HIP_MEMORY_SCOPE_AGENT);
    } else {
        if (threadIdx.x == 0) {
            asm volatile("s_waitcnt vmcnt(0)" ::: "memory");
            __hip_atomic_store(&flags[blockIdx.x * 32], gval, __ATOMIC_RELAXED,
                               __HIP_MEMORY_SCOPE_AGENT);
            while (__hip_atomic_load(&gen8[(blockIdx.x & 7) * 32],
                                     __ATOMIC_RELAXED,
                                     __HIP_MEMORY_SCOPE_AGENT) < gval)
                __builtin_amdgcn_s_sleep(2);
        }
        __syncthreads();
    }
}

// ---------------- fused MP: 8 edge iters -> node-all -> final ----------------
__global__ __launch_bounds__(512, 4) void mp_fused_kernel(
    const float* __restrict__ u, float* __restrict__ Sbuf,
    const float* __restrict__ pT, const float* __restrict__ p,
    const int* __restrict__ edges, const int* __restrict__ wflag,
    int* __restrict__ aidx, float* __restrict__ q,
    float* __restrict__ a_out, float* __restrict__ q_out,
    int* __restrict__ flags)
{
    const int tid = threadIdx.x;
    const int bid = blockIdx.x;
    const int e   = bid * 32 + (tid >> 4);   // 0..15999
    const int L   = tid & 15;

    // ---- persistent per-edge state (registers) ----
    const int gi = edges[2 * e], gj = edges[2 * e + 1];
    const int wf = wflag[e];
    const float4* pt = (const float4*)(pT + e * 256 + L * 16);
    const float4 p0 = pt[0], p1 = pt[1], p2 = pt[2], p3 = pt[3];
    float pv[16] = {p0.x, p0.y, p0.z, p0.w, p1.x, p1.y, p1.z, p1.w,
                    p2.x, p2.y, p2.z, p2.w, p3.x, p3.y, p3.z, p3.w};
    float vmax = -INFINITY;
    #pragma unroll
    for (int a = 0; a < 16; ++a) vmax = fmaxf(vmax, pv[a]);
    float mold_ij = 0.f, mold_ji = 0.f;      // prior mi / mj (replaces msg[])

    for (int t = 0; t < NITERS; ++t) {
        // ---- edge phase, iter t ----
        const float* uSo = Sbuf + t * 32000;
        float* uSn = Sbuf + (t + 1) * 32000;
        const float bi = uSo[gi * 16 + L] - mold_ij;
        const float bj = uSo[gj * 16 + L] - mold_ji;
        float mj = -INFINITY;
        #pragma unroll
        for (int a = 0; a < 16; ++a)
            mj = fmaxf(mj, pv[a] + __shfl(bi, a, 16));
        float mi = vmax + bj;
        float sj = mj, si = mi;
        #pragma unroll
        for (int off = 1; off < 16; off <<= 1) {
            sj += __shfl_xor(sj, off, 16);
            si += __shfl_xor(si, off, 16);
        }
        mj -= sj * (1.f / 16.f);
        mi -= si * (1.f / 16.f);
        mold_ji = mj;
        mold_ij = mi;
        if (wf) {
            atomicAdd(&uSn[gj * 16 + L], mj);
            atomicAdd(&uSn[gi * 16 + L], mi);
        }
        grid_bar(flags, t + 1);              // Sbuf[t+1] complete
    }

    // ---- node-all: blocks 0..287, one t per 36-block group ----
    if (bid < 288) {
        const int t2 = bid / 36;             // 0..7
        const int r2 = (bid % 36) * 512 + tid;
        const float* Sn = Sbuf + (t2 + 1) * 32000;   // = u + S[t2]
        float partial = 0.f;
        if (r2 < N_NODES) {
            int n = r2;
            float bv = Sn[n * 16];
            int best = 0;
            #pragma unroll
            for (int a = 1; a < 16; ++a) {
                float v = Sn[n * 16 + a];
                if (v > bv) { bv = v; best = a; }
            }
            __hip_atomic_store(&aidx[t2 * N_NODES + n], best, __ATOMIC_RELAXED,
                               __HIP_MEMORY_SCOPE_AGENT);   // L2-bypass store
            partial = u[n * 16 + best];
        } else if (r2 < N_NODES + NE) {
            int ee = r2 - N_NODES;
            int ii = edges[2 * ee], jj = edges[2 * ee + 1];
            float bvi = Sn[ii * 16]; int ai = 0;
            #pragma unroll
            for (int a = 1; a < 16; ++a) {
                float v = Sn[ii * 16 + a];
                if (v > bvi) { bvi = v; ai = a; }
            }
            float bvj = Sn[jj * 16]; int aj = 0;
            #pragma unroll
            for (int a = 1; a < 16; ++a) {
                float v = Sn[jj * 16 + a];
                if (v > bvj) { bvj = v; aj = a; }
            }
            partial = p[ee * 256 + ai * 16 + aj];
        }
        #pragma unroll
        for (int off = 1; off < 64; off <<= 1)
            partial += __shfl_xor(partial, off, 64);
        if ((tid & 63) == 0) atomicAdd(&q[t2], partial);
    }
    grid_bar(flags, NITERS + 1);             // all q[t], aidx final

    // ---- final: running strict-> max over iters, one-hot a ----
    const int r = bid * 512 + tid;
    if (r < N_NODES * 16) {
        float cur = 0.f; int best_t = -1;
        #pragma unroll
        for (int t2 = 0; t2 < NITERS; ++t2) {
            float qv = q[t2];
            if (qv > cur) { cur = qv; best_t = t2; }
        }
        int n = r >> 4, c = r & 15;
        float val = 0.f;
        if (best_t >= 0 && aidx[best_t * N_NODES + n] == c) val = 1.f;
        a_out[r] = val;
        if (r == 0) q_out[0] = cur;
    }
}

extern "C" void kernel_launch(void* const* d_in, const int* in_sizes, int n_in,
                              void* d_out, int out_size, void* d_ws, size_t ws_size,
                              hipStream_t stream)
{
    (void)in_sizes; (void)n_in; (void)out_size; (void)ws_size;
    const float* x    = (const float*)d_in[0];
    const float* pa   = (const float*)d_in[1];
    const float* st   = (const float*)d_in[2];
    const int*   edges= (const int*)d_in[3];
    const float* gwih = (const float*)d_in[4];
    const float* gwhh = (const float*)d_in[5];
    const float* gbih = (const float*)d_in[6];
    const float* gbhh = (const float*)d_in[7];
    const float* uW0 = (const float*)d_in[8];  const float* ub0 = (const float*)d_in[9];
    const float* uW1 = (const float*)d_in[10]; const float* ub1 = (const float*)d_in[11];
    const float* uW2 = (const float*)d_in[12]; const float* ub2 = (const float*)d_in[13];
    const float* pW0 = (const float*)d_in[14]; const float* pb0 = (const float*)d_in[15];
    const float* pW1 = (const float*)d_in[16]; const float* pb1 = (const float*)d_in[17];
    const float* pW2 = (const float*)d_in[18]; const float* pb2 = (const float*)d_in[19];
    const float* pW3 = (const float*)d_in[20]; const float* pb3 = (const float*)d_in[21];
    const float* pW4 = (const float*)d_in[22]; const float* pb4 = (const float*)d_in[23];

    float* out   = (float*)d_out;
    float* a_out = out;                 // 32000
    float* q_out = out + 32000;         // 1
    float* u_out = out + 32001;         // 32000
    float* p_out = out + 64001;         // 4,096,000
    float* h_out = out + 4160001;       // 256,000 (state_out)

    float* ws   = (float*)d_ws;
    float* Sbuf = ws + WS_SBUF;
    float* q    = ws + WS_Q;
    int*   flg  = (int*)(ws + WS_FLAGS);
    int*   aidx = (int*)(ws + WS_AIDX);
    int*   wfl  = (int*)(ws + WS_W);
    float* pT   = ws + WS_PT;
    float* cab  = ws + WS_CAB;
    int*   owner= (int*)(ws + WS_PT);   // aliases pT; dead before pmlp runs

    setup_kernel<<<1087, 256, 0, stream>>>(ws, edges, uW0, uW1, uW2,
                                           pW0, pW1, pW2, pW3, pW4, gwih, gwhh);
    gru_kernel<<<313, 256, 0, stream>>>(x, pa, st, ws + WS_GIT, ws + WS_GHT,
                                        gbih, gbhh, h_out, edges, owner);
    umlp_kernel<<<563, 256, 0, stream>>>(h_out, ws + WS_UW0T, ub0,
                                         ws + WS_UW1T, ub1, ws + WS_UW2T, ub2,
                                         ws + WS_UWCAT, u_out, Sbuf, cab,
                                         edges, owner, wfl);
    pmlp_kernel<<<NE / 32, 512, 0, stream>>>(cab, edges, pb0,
                                             (const _Float16*)ws,
                                             pb1, pb2, pb3, pb4, p_out, pT);
    mp_fused_kernel<<<NBLK, 512, 0, stream>>>(u_out, Sbuf, pT, p_out,
                                              edges, wfl, aidx, q,
                                              a_out, q_out, flg);
}